// Round 5
// baseline (242.426 us; speedup 1.0000x reference)
//
#include <hip/hip_runtime.h>
#include <hip/hip_bf16.h>
#include <hip/hip_cooperative_groups.h>

namespace cg = cooperative_groups;

// Problem constants (fixed by reference):
//   x[N=8][INC=32][INN=50000] fp32, A[OUTN=8192][MAXD=16] int32,
//   mask[OUTN][MAXD][1] fp32, weight[INC=32][OUTC=32] fp32, bias[OUTC=32][OUTN=8192]
//   out[N=8][OUTC=32][OUTN=8192] fp32
// R9: single cooperative kernel = {phase A: transpose x -> xt bf16 (R7 K1 body,
//     256-thr subgroups, 3128 tile-jobs)} grid.sync() {phase B: gather+pool+
//     matmul (R7 K2 body, TO=32)}. Purpose: (a) remove inter-kernel launch/drain
//     bubble, (b) make total kernel time visible in the top-5 profile cut
//     (attribution: fused duration vs the fixed 43us poison fill). R8's losers
//     (782-block K1, shfl_xor parity gather) reverted to R7 form. Fallback to
//     the proven two-kernel path if cooperative launch is rejected.

#define INN   50000
#define NR    256        // N*INC rows
#define OUTN  8192
#define MAXD  16
#define TO    32         // output nodes per block in phase B
#define NBLK  256
#define NTHR  1024
#define NJOBS 3128       // 782 i-tiles x 4 r-tiles

static __device__ __forceinline__ float bf2f(unsigned short u) {
    return __uint_as_float(((unsigned int)u) << 16);
}
static __device__ __forceinline__ unsigned pack2(float a, float b) {
    const unsigned lo = (unsigned)__bfloat16_as_ushort(__float2bfloat16(a));
    const unsigned hi = (unsigned)__bfloat16_as_ushort(__float2bfloat16(b));
    return lo | (hi << 16);
}

// ---- shared-memory arena (phases disjoint; offsets 16B-aligned) ----
//   phase A: 4 transpose tiles of 64*65 floats (16640 B each) = 66560 B
//   phase B: pooled[TO*260] (33280) + Wt[32*36] (4608) + Ash (2048) + Msh (2048)
#define SH_BYTES (4 * 64 * 65 * 4)

// =================== transpose tile body (R7 K1, per 256-thr group) =========
static __device__ __forceinline__ void tile_load(const float* __restrict__ x,
                                                 float* tile, int tl, int i0, int r0,
                                                 bool active) {
    const int i4l = tl & 15;
    const int rl0 = tl >> 4;
    const float4* x4 = (const float4*)x;
    const int i4base = (i0 >> 2) + i4l;
    const bool iv = active && (i4base < (INN / 4));   // INN % 4 == 0
    for (int k = 0; k < 4; ++k) {
        const int rl = rl0 + 16 * k;
        float4 v = iv ? x4[(size_t)(r0 + rl) * (INN / 4) + i4base]
                      : make_float4(0.f, 0.f, 0.f, 0.f);
        const int ib = i4l * 4;
        tile[(ib + 0) * 65 + rl] = v.x;
        tile[(ib + 1) * 65 + rl] = v.y;
        tile[(ib + 2) * 65 + rl] = v.z;
        tile[(ib + 3) * 65 + rl] = v.w;
    }
}
static __device__ __forceinline__ void tile_store(unsigned short* __restrict__ xt,
                                                  const float* tile, int tl, int i0, int r0,
                                                  bool active) {
    const int r8l = tl & 7;
    const int il0 = tl >> 3;
    for (int k = 0; k < 2; ++k) {
        const int il = il0 + 32 * k;
        const int i  = i0 + il;
        if (active && i < INN) {
            const float* src = &tile[il * 65 + r8l * 8];
            uint4 b;
            b.x = pack2(src[0], src[1]);
            b.y = pack2(src[2], src[3]);
            b.z = pack2(src[4], src[5]);
            b.w = pack2(src[6], src[7]);
            *(uint4*)&xt[(size_t)i * NR + r0 + 8 * r8l] = b;
        }
    }
}

// =================== fused cooperative kernel ===============================
__global__ __launch_bounds__(NTHR) void fused(const float* __restrict__ x,
                                              const int*   __restrict__ A,
                                              const float* __restrict__ mask,
                                              const float* __restrict__ W,
                                              const float* __restrict__ bias,
                                              float* __restrict__ out,
                                              unsigned short* __restrict__ xt) {
    __shared__ __align__(16) char shraw[SH_BYTES];
    const int t   = threadIdx.x;
    const int bid = blockIdx.x;

    // ---------------- phase A: transpose x -> xt --------------------------
    {
        const int sg = t >> 8;        // subgroup 0..3, one 64x64 tile each
        const int tl = t & 255;
        float* tile = (float*)shraw + sg * (64 * 65);
        for (int it = 0; it < 4; ++it) {
            const int job = it * (NBLK * 4) + bid * 4 + sg;   // 0..4095
            const bool active = (job < NJOBS);
            const int jb = active ? job : 0;
            const int i0 = (jb % 782) * 64;
            const int r0 = (jb / 782) * 64;
            tile_load(x, tile, tl, i0, r0, active);
            __syncthreads();
            tile_store(xt, tile, tl, i0, r0, active);
            __syncthreads();
        }
    }

    __threadfence();               // make xt visible device-wide (cross-XCD)
    cg::this_grid().sync();

    // ---------------- phase B: gather + pool + 32x32 matmul + bias --------
    float* pooled = (float*)shraw;                       // TO*260 floats
    float* Wt     = (float*)shraw + TO * 260;            // 32*36
    int*   Ash    = (int*)((float*)shraw + TO * 260 + 32 * 36);
    float* Msh    = (float*)shraw + TO * 260 + 32 * 36 + TO * MAXD;

    const int o0 = bid * TO;

    if (t < TO * MAXD) {
        Ash[t] = A[o0 * MAXD + t];
        Msh[t] = mask[o0 * MAXD + t];
    }
    {
        const int c = t >> 5, cd = t & 31;
        Wt[cd * 36 + c] = W[t];          // t covers all 1024 weights
    }
    __syncthreads();

    // gather: 16 wave-groups x 2 nodes; all 16 row loads issued before consume
    {
        const int j  = t & 63;
        const int og = t >> 6;
        const ushort4* xt4 = (const ushort4*)xt;   // row pitch = 64 ushort4
        for (int m = 0; m < 2; ++m) {
            const int ol = og * 2 + m;
            ushort4 u[MAXD];
#pragma unroll
            for (int d = 0; d < MAXD; ++d) {
                const int idx = Ash[ol * MAXD + d];   // wave-uniform -> broadcast
                u[d] = xt4[(size_t)idx * 64 + j];
            }
            float4 a = make_float4(0.f, 0.f, 0.f, 0.f);
#pragma unroll
            for (int d = 0; d < MAXD; ++d) {
                const float s = Msh[ol * MAXD + d];
                a.x += s * bf2f(u[d].x);
                a.y += s * bf2f(u[d].y);
                a.z += s * bf2f(u[d].z);
                a.w += s * bf2f(u[d].w);
            }
            *(float4*)&pooled[ol * 260 + 4 * j] = a;
        }
    }
    __syncthreads();

    // matmul epilogue (t<256): thread = (n, cd); full 128B out runs per lane
    if (t < 256) {
        const int n  = t >> 5;
        const int cd = t & 31;
        float4 w[8];
#pragma unroll
        for (int cc = 0; cc < 8; ++cc)
            w[cc] = *(const float4*)&Wt[cd * 36 + 4 * cc];

        float res[TO];
#pragma unroll
        for (int ol = 0; ol < TO; ++ol) {
            const float4* pr = (const float4*)&pooled[ol * 260 + n * 32];
            float s = 0.f;
#pragma unroll
            for (int cc = 0; cc < 8; ++cc) {
                const float4 p = pr[cc];
                s += p.x * w[cc].x + p.y * w[cc].y + p.z * w[cc].z + p.w * w[cc].w;
            }
            res[ol] = s;
        }

        const size_t obase = (size_t)n * (32 * OUTN) + (size_t)cd * OUTN + o0;
        const size_t bbase = (size_t)cd * OUTN + o0;
#pragma unroll
        for (int q = 0; q < 8; ++q) {
            const float4 b = *(const float4*)&bias[bbase + 4 * q];
            float4 r;
            r.x = res[4 * q + 0] + b.x;
            r.y = res[4 * q + 1] + b.y;
            r.z = res[4 * q + 2] + b.z;
            r.w = res[4 * q + 3] + b.w;
            *(float4*)&out[obase + 4 * q] = r;
        }
    }
}

// =================== fallback two-kernel path (R7, proven 113.0us) ==========
__global__ __launch_bounds__(256) void transpose_x(const float* __restrict__ x,
                                                   unsigned short* __restrict__ xt) {
    __shared__ float tile[64 * 65];
    const int t  = threadIdx.x;
    const int i0 = blockIdx.x * 64;
    const int r0 = blockIdx.y * 64;
    tile_load(x, tile, t, i0, r0, true);
    __syncthreads();
    tile_store(xt, tile, t, i0, r0, true);
}

__global__ __launch_bounds__(1024) void gather_gemm(const unsigned short* __restrict__ xt,
                                                    const int*   __restrict__ A,
                                                    const float* __restrict__ mask,
                                                    const float* __restrict__ W,
                                                    const float* __restrict__ bias,
                                                    float* __restrict__ out) {
    __shared__ float pooled[TO * 260];
    __shared__ float Wt[32 * 36];
    __shared__ int   Ash[TO * MAXD];
    __shared__ float Msh[TO * MAXD];

    const int t  = threadIdx.x;
    const int o0 = blockIdx.x * TO;

    if (t < TO * MAXD) {
        Ash[t] = A[o0 * MAXD + t];
        Msh[t] = mask[o0 * MAXD + t];
    }
    {
        const int c = t >> 5, cd = t & 31;
        Wt[cd * 36 + c] = W[t];
    }
    __syncthreads();

    {
        const int j  = t & 63;
        const int og = t >> 6;
        const ushort4* xt4 = (const ushort4*)xt;
        for (int m = 0; m < 2; ++m) {
            const int ol = og * 2 + m;
            ushort4 u[MAXD];
#pragma unroll
            for (int d = 0; d < MAXD; ++d) {
                const int idx = Ash[ol * MAXD + d];
                u[d] = xt4[(size_t)idx * 64 + j];
            }
            float4 a = make_float4(0.f, 0.f, 0.f, 0.f);
#pragma unroll
            for (int d = 0; d < MAXD; ++d) {
                const float s = Msh[ol * MAXD + d];
                a.x += s * bf2f(u[d].x);
                a.y += s * bf2f(u[d].y);
                a.z += s * bf2f(u[d].z);
                a.w += s * bf2f(u[d].w);
            }
            *(float4*)&pooled[ol * 260 + 4 * j] = a;
        }
    }
    __syncthreads();

    if (t < 256) {
        const int n  = t >> 5;
        const int cd = t & 31;
        float4 w[8];
#pragma unroll
        for (int cc = 0; cc < 8; ++cc)
            w[cc] = *(const float4*)&Wt[cd * 36 + 4 * cc];

        float res[TO];
#pragma unroll
        for (int ol = 0; ol < TO; ++ol) {
            const float4* pr = (const float4*)&pooled[ol * 260 + n * 32];
            float s = 0.f;
#pragma unroll
            for (int cc = 0; cc < 8; ++cc) {
                const float4 p = pr[cc];
                s += p.x * w[cc].x + p.y * w[cc].y + p.z * w[cc].z + p.w * w[cc].w;
            }
            res[ol] = s;
        }

        const size_t obase = (size_t)n * (32 * OUTN) + (size_t)cd * OUTN + o0;
        const size_t bbase = (size_t)cd * OUTN + o0;
#pragma unroll
        for (int q = 0; q < 8; ++q) {
            const float4 b = *(const float4*)&bias[bbase + 4 * q];
            float4 r;
            r.x = res[4 * q + 0] + b.x;
            r.y = res[4 * q + 1] + b.y;
            r.z = res[4 * q + 2] + b.z;
            r.w = res[4 * q + 3] + b.w;
            *(float4*)&out[obase + 4 * q] = r;
        }
    }
}

extern "C" void kernel_launch(void* const* d_in, const int* in_sizes, int n_in,
                              void* d_out, int out_size, void* d_ws, size_t ws_size,
                              hipStream_t stream) {
    const float* x    = (const float*)d_in[0];
    const int*   A    = (const int*)  d_in[1];
    const float* mask = (const float*)d_in[2];
    const float* W    = (const float*)d_in[3];
    const float* bias = (const float*)d_in[4];
    float* out = (float*)d_out;
    unsigned short* xt = (unsigned short*)d_ws;   // 50000*256*2 = 25.6 MB scratch

    void* args[] = { (void*)&x, (void*)&A, (void*)&mask, (void*)&W,
                     (void*)&bias, (void*)&out, (void*)&xt };
    hipError_t e = hipLaunchCooperativeKernel((const void*)fused, dim3(NBLK),
                                              dim3(NTHR), args, 0, stream);
    if (e != hipSuccess) {
        // fallback: proven R7 two-kernel path
        transpose_x<<<dim3(782, 4), 256, 0, stream>>>(x, xt);
        gather_gemm<<<OUTN / TO, 1024, 0, stream>>>(xt, A, mask, W, bias, out);
    }
}

// Round 6
// 111.725 us; speedup vs baseline: 2.1698x; 2.1698x over previous
//
#include <hip/hip_runtime.h>
#include <hip/hip_bf16.h>

// Problem constants (fixed by reference):
//   x[N=8][INC=32][INN=50000] fp32, A[OUTN=8192][MAXD=16] int32,
//   mask[OUTN][MAXD][1] fp32, weight[INC=32][OUTC=32] fp32, bias[OUTC=32][OUTN=8192]
//   out[N=8][OUTC=32][OUTN=8192] fp32
// K1: transpose x -> xt[INN][256] bf16 (row j = n*32+c).  K2: gather+pool+matmul fp32.
// R10: REVERT to the session-best round-0 configuration (111.47us measured).
//   R9 (cooperative fusion) regressed to 242us but delivered attribution:
//   total HBM traffic ~92 MB (floor ~15us), VALU 5%, conflicts negligible ->
//   K1+K2 ~27us combined; the rest of the 113 is the fixed 43us ws-poison fill
//   plus ~40us of harness reset()/launch overhead outside kernel_launch.
//   R6/R7/R8/R9 variants (load batching, TO=8/32, 1024thr, 16B xt stores,
//   parity-split gather, coop fusion) were all neutral-to-negative.

#define INN   50000
#define NR    256        // N*INC rows
#define OUTN  8192
#define MAXD  16
#define TO    16         // output nodes per block in K2

static __device__ __forceinline__ float bf2f(unsigned short u) {
    return __uint_as_float(((unsigned int)u) << 16);
}

// ---------------- Kernel 1: transpose x[256][50000] -> xt_bf16[50000][256] ----
// 64(i) x 64(r) tile, float4 loads along i, ushort4 (bf16x4) stores along r.
// LDS pitch 65: load-scatter and store-gather are <=2-way bank-aliased (free).
__global__ __launch_bounds__(256) void transpose_x(const float* __restrict__ x,
                                                   unsigned short* __restrict__ xt) {
    __shared__ float tile[64 * 65];
    const int t  = threadIdx.x;
    const int i0 = blockIdx.x * 64;   // column (INN) tile base
    const int r0 = blockIdx.y * 64;   // row tile base (always < 256)

    // ---- load: lanes sweep i (coalesced float4), 16 rows per k-step
    {
        const int i4l = t & 15;        // which float4 within the 64-wide i tile
        const int rl0 = t >> 4;        // row within tile
        const float4* x4 = (const float4*)x;
        const int i4base = (i0 >> 2) + i4l;
        const bool iv = (i4base < (INN / 4));   // INN % 4 == 0
        for (int k = 0; k < 4; ++k) {
            const int rl = rl0 + 16 * k;
            float4 v = iv ? x4[(size_t)(r0 + rl) * (INN / 4) + i4base]
                          : make_float4(0.f, 0.f, 0.f, 0.f);
            const int ib = i4l * 4;
            tile[(ib + 0) * 65 + rl] = v.x;
            tile[(ib + 1) * 65 + rl] = v.y;
            tile[(ib + 2) * 65 + rl] = v.z;
            tile[(ib + 3) * 65 + rl] = v.w;
        }
    }
    __syncthreads();
    // ---- store: lanes sweep r (coalesced ushort4 = 8B/lane)
    {
        const int r4l = t & 15;
        const int il0 = t >> 4;
        for (int k = 0; k < 4; ++k) {
            const int il = il0 + 16 * k;
            const int i  = i0 + il;
            if (i < INN) {
                ushort4 b;
                b.x = __bfloat16_as_ushort(__float2bfloat16(tile[il * 65 + r4l * 4 + 0]));
                b.y = __bfloat16_as_ushort(__float2bfloat16(tile[il * 65 + r4l * 4 + 1]));
                b.z = __bfloat16_as_ushort(__float2bfloat16(tile[il * 65 + r4l * 4 + 2]));
                b.w = __bfloat16_as_ushort(__float2bfloat16(tile[il * 65 + r4l * 4 + 3]));
                *(ushort4*)&xt[(size_t)i * NR + r0 + 4 * r4l] = b;
            }
        }
    }
}

// ---------------- Kernel 2: gather + masked pool + 32x32 matmul + bias ------
// One block = 16 output nodes, 512 threads (8 waves) -> 16 waves/CU for
// latency hiding on the random-index gather. Phase 2 on t<256 with each lane
// owning a full 64B output run.
__global__ __launch_bounds__(512) void gather_gemm(const unsigned short* __restrict__ xt,
                                                   const int*   __restrict__ A,
                                                   const float* __restrict__ mask,
                                                   const float* __restrict__ W,
                                                   const float* __restrict__ bias,
                                                   float* __restrict__ out) {
    // pooled pitch 260: 16B-aligned rows; every LDS op <=2-way aliased (free).
    __shared__ float pooled[TO * 260];
    __shared__ float Wt[32 * 36];      // Wt[cd][c], pitch 36 (16B aligned rows)
    __shared__ int   Ash[TO * MAXD];
    __shared__ float Msh[TO * MAXD];

    const int t  = threadIdx.x;
    const int o0 = blockIdx.x * TO;

    // stage A, mask (256 entries each), and transposed W (1024 weights)
    if (t < 256) {
        Ash[t] = A[o0 * MAXD + t];
        Msh[t] = mask[o0 * MAXD + t];
    }
    for (int k = 0; k < 2; ++k) {
        const int idx = t + 512 * k;
        const int c = idx >> 5, cd = idx & 31;
        Wt[cd * 36 + c] = W[idx];
    }
    __syncthreads();

    // ---- phase 1: gather bf16 rows of xt (512B = full row per wave-instruction)
    // 8 wave-groups x 2 nodes each.
    {
        const int j  = t & 63;                 // ushort4 column within row
        const int og = t >> 6;                 // 8 wave-groups
        const ushort4* xt4 = (const ushort4*)xt;   // row pitch = 64 ushort4
        for (int m = 0; m < 2; ++m) {
            const int ol = og * 2 + m;
            float4 a = make_float4(0.f, 0.f, 0.f, 0.f);
#pragma unroll
            for (int d = 0; d < MAXD; ++d) {
                const int   idx = Ash[ol * MAXD + d];   // wave-uniform -> broadcast
                const float s   = Msh[ol * MAXD + d];
                const ushort4 u = xt4[(size_t)idx * 64 + j];
                a.x += s * bf2f(u.x);
                a.y += s * bf2f(u.y);
                a.z += s * bf2f(u.z);
                a.w += s * bf2f(u.w);
            }
            *(float4*)&pooled[ol * 260 + 4 * j] = a;
        }
    }
    __syncthreads();

    // ---- phase 2 (t<256 only): thread = (n, cd). 32-term dot per node,
    // each lane writes a full 64B run of out. Phase 2 is ~1% of the kernel,
    // idling waves 4..7 here is free.
    if (t < 256) {
        const int n  = t >> 5;   // 0..7
        const int cd = t & 31;   // 0..31
        float4 w[8];
#pragma unroll
        for (int cc = 0; cc < 8; ++cc)
            w[cc] = *(const float4*)&Wt[cd * 36 + 4 * cc];

        float res[TO];
#pragma unroll
        for (int ol = 0; ol < TO; ++ol) {
            const float4* pr = (const float4*)&pooled[ol * 260 + n * 32];
            float s = 0.f;
#pragma unroll
            for (int cc = 0; cc < 8; ++cc) {
                const float4 p = pr[cc];       // 2 addrs/wave -> LDS broadcast
                s += p.x * w[cc].x + p.y * w[cc].y + p.z * w[cc].z + p.w * w[cc].w;
            }
            res[ol] = s;
        }

        const size_t obase = (size_t)n * (32 * OUTN) + (size_t)cd * OUTN + o0;
        const size_t bbase = (size_t)cd * OUTN + o0;
#pragma unroll
        for (int q = 0; q < 4; ++q) {
            const float4 b = *(const float4*)&bias[bbase + 4 * q];
            float4 r;
            r.x = res[4 * q + 0] + b.x;
            r.y = res[4 * q + 1] + b.y;
            r.z = res[4 * q + 2] + b.z;
            r.w = res[4 * q + 3] + b.w;
            *(float4*)&out[obase + 4 * q] = r;
        }
    }
}

extern "C" void kernel_launch(void* const* d_in, const int* in_sizes, int n_in,
                              void* d_out, int out_size, void* d_ws, size_t ws_size,
                              hipStream_t stream) {
    const float* x    = (const float*)d_in[0];
    const int*   A    = (const int*)  d_in[1];
    const float* mask = (const float*)d_in[2];
    const float* W    = (const float*)d_in[3];
    const float* bias = (const float*)d_in[4];
    float* out = (float*)d_out;
    unsigned short* xt = (unsigned short*)d_ws;   // 50000*256*2 = 25.6 MB scratch

    // K1: 782 i-tiles (ceil(50000/64)) x 4 r-tiles
    transpose_x<<<dim3(782, 4), 256, 0, stream>>>(x, xt);
    // K2: 8192/16 = 512 blocks x 512 threads
    gather_gemm<<<OUTN / TO, 512, 0, stream>>>(xt, A, mask, W, bias, out);
}